// Round 20
// baseline (917.414 us; speedup 1.0000x reference)
//
#include <hip/hip_runtime.h>
#include <hip/hip_bf16.h>
#include <cstddef>

#define HIDDEN 512
#define ATOM_FDIM 133
#define BOND_FDIM 14
#define FB_DIM 147
#define MAX_NB 6
#define BM 64
#define BMI 128     // igemm row tile
#define TROW 520    // padded bf16 row pitch for transpose buffer
#define NCH 24      // A chunks: K=192 pad (tiles 0..5; tile5 = bondsum x Wh2)

typedef __attribute__((ext_vector_type(8)))  short         s16x8;
typedef __attribute__((ext_vector_type(16))) char          c8x16;
typedef __attribute__((ext_vector_type(8)))  signed char   s8x8;
typedef __attribute__((ext_vector_type(4)))  float         f32x4;
typedef __attribute__((ext_vector_type(4)))  int           i32x4;

__device__ __forceinline__ float uf(unsigned short u) {
    return __uint_as_float(((unsigned)u) << 16);
}
__device__ __forceinline__ unsigned short fb(float f) {
    __hip_bfloat16 h = __float2bfloat16(f);
    return *reinterpret_cast<unsigned short*>(&h);
}

// LDS A tile: chunks(16B) x 64 rows, XOR-swizzled.
#define A_UNIT(ch, row) (((ch) << 6) + ((row) ^ ((ch) & 7)))

// ---------------------------------------------------------------------------
// bf16 weight convert: f32 [Ksrc][512] -> bf16 MFMA-fragment order (K=32 tiles)
// ---------------------------------------------------------------------------
__global__ __launch_bounds__(256) void cvt_w(const float* __restrict__ src,
                                             unsigned short* __restrict__ dst,
                                             int Ksrc, int nchunks)
{
    int c = blockIdx.x * 256 + threadIdx.x;
    if (c >= nchunks) return;
    int tile = c >> 11, pc = c & 2047, n = pc >> 2, s = pc & 3;
    s16x8 o;
    #pragma unroll
    for (int e = 0; e < 8; e++) {
        int k = tile * 32 + s * 8 + e;
        float v = (k < Ksrc) ? src[(size_t)k * HIDDEN + n] : 0.f;
        o[e] = (short)fb(v);
    }
    reinterpret_cast<s16x8*>(dst)[c] = o;
}

// ---------------------------------------------------------------------------
// Fused per-column scale + i8 convert: one block per column n.
// ---------------------------------------------------------------------------
__global__ __launch_bounds__(256) void cvt8_k(const float* __restrict__ src,
                                              signed char* __restrict__ dst,
                                              float* __restrict__ wsc)
{
    int n = blockIdx.x;
    float v0 = src[(size_t)threadIdx.x * HIDDEN + n];
    float v1 = src[(size_t)(threadIdx.x + 256) * HIDDEN + n];
    float m = fmaxf(fabsf(v0), fabsf(v1));
    #pragma unroll
    for (int off = 32; off; off >>= 1) m = fmaxf(m, __shfl_down(m, off));
    __shared__ float red[4];
    __shared__ float bcast;
    if ((threadIdx.x & 63) == 0) red[threadIdx.x >> 6] = m;
    __syncthreads();
    if (threadIdx.x == 0) {
        m = fmaxf(fmaxf(red[0], red[1]), fmaxf(red[2], red[3]));
        bcast = m;
        wsc[n] = m / 127.f;
    }
    __syncthreads();
    float mx = bcast;
    float inv = (mx > 0.f) ? 127.f / mx : 0.f;
    #pragma unroll
    for (int h = 0; h < 2; h++) {
        int k = threadIdx.x + h * 256;
        float v = (h == 0) ? v0 : v1;
        int q = (int)rintf(v * inv);
        q = (q > 127) ? 127 : ((q < -127) ? -127 : q);
        int tile = k >> 6, g = (k & 63) >> 4, e = k & 15;
        dst[((size_t)tile * 2048 + n * 4 + g) * 16 + e] = (char)q;
    }
}

// ---------------------------------------------------------------------------
// Prologue GEMM, sequential accumulator, half-width B buffering:
//   stage A once: atomf (k<133) + bond-sum gather (k in [160,174), fused)
//   acc = A@WiT[0..4]        -> msgQ = i8 quant(relu(acc)), flags
//   acc += A@WiT[5] (=Wh2)   -> baseQ = i8 rowwise-absmax quant(acc)
//   acc  = A@Wo1T[0..4]      -> foB  = bf16(acc + b_o)  [nontemporal]
// ---------------------------------------------------------------------------
__global__ __launch_bounds__(512, 4) void pro_k(
    const float* __restrict__ Af32,
    const float* __restrict__ fbonds, const int* __restrict__ a2b,
    const unsigned short* __restrict__ WiT,    // 6 tiles
    const unsigned short* __restrict__ Wo1T,   // 5 tiles
    const float* __restrict__ bias,
    signed char* __restrict__ baseQ, float* __restrict__ bqscale,
    unsigned short* __restrict__ foB,
    signed char* __restrict__ qout, float* __restrict__ qscale,
    float* __restrict__ flags,
    int M)
{
    __shared__ s16x8 As[NCH * 64];               // 24 KB, lives whole kernel
    __shared__ char  tbuf[TROW * 32 * 2];        // 33.3 KB: transpose / quant
    __shared__ float rmax[BM][4];

    const int t    = threadIdx.x;
    const int m0   = blockIdx.x * BM;
    const int lane = t & 63;
    const int l15  = lane & 15, lhi = lane >> 4;
    const int w    = t >> 6, wm = w >> 2, wn = w & 3;
    const int rs   = t >> 3, oc = t & 7;

    f32x4 acc[2][8];
    #pragma unroll
    for (int mr = 0; mr < 2; mr++)
        #pragma unroll
        for (int nr = 0; nr < 8; nr++)
            acc[mr][nr] = (f32x4){0.f, 0.f, 0.f, 0.f};

    // one MFMA K-tile with HALF-width (4-fragment) B buffering
#define TMFMA(WTP, TILE) do {                                                 \
    s16x8 a0_ = As[A_UNIT((TILE) * 4 + lhi, wm * 32 + l15)];                  \
    s16x8 a1_ = As[A_UNIT((TILE) * 4 + lhi, wm * 32 + 16 + l15)];             \
    _Pragma("unroll")                                                         \
    for (int h_ = 0; h_ < 2; ++h_) {                                          \
        s16x8 b_[4];                                                          \
        const s16x8* bb_ = reinterpret_cast<const s16x8*>(                    \
            (WTP) + (size_t)(TILE) * (HIDDEN * 32))                           \
            + ((wn * 128 + h_ * 64 + l15) * 4 + lhi);                         \
        _Pragma("unroll")                                                     \
        for (int nr_ = 0; nr_ < 4; nr_++) b_[nr_] = bb_[nr_ * 64];            \
        _Pragma("unroll")                                                     \
        for (int nr_ = 0; nr_ < 4; nr_++) {                                   \
            acc[0][h_ * 4 + nr_] = __builtin_amdgcn_mfma_f32_16x16x32_bf16(   \
                a0_, b_[nr_], acc[0][h_ * 4 + nr_], 0, 0, 0);                 \
            acc[1][h_ * 4 + nr_] = __builtin_amdgcn_mfma_f32_16x16x32_bf16(   \
                a1_, b_[nr_], acc[1][h_ * 4 + nr_], 0, 0, 0);                 \
        }                                                                     \
    }                                                                         \
} while (0)

    // i8 row-quant of acc into QOUT/QSC.  SIGNED: use |.|; UNSIGNED: relu.
#define QUANT8(QOUT, QSC, SIGNED) do {                                        \
    _Pragma("unroll")                                                         \
    for (int mr = 0; mr < 2; mr++)                                            \
        _Pragma("unroll")                                                     \
        for (int rg = 0; rg < 4; rg++) {                                      \
            float pm = 0.f;                                                   \
            _Pragma("unroll")                                                 \
            for (int nr = 0; nr < 8; nr++)                                    \
                pm = fmaxf(pm, (SIGNED) ? fabsf(acc[mr][nr][rg])              \
                                        : acc[mr][nr][rg]);                   \
            pm = fmaxf(pm, __shfl_xor(pm, 1));                                \
            pm = fmaxf(pm, __shfl_xor(pm, 2));                                \
            pm = fmaxf(pm, __shfl_xor(pm, 4));                                \
            pm = fmaxf(pm, __shfl_xor(pm, 8));                                \
            if (l15 == 0) rmax[wm * 32 + mr * 16 + lhi * 4 + rg][wn] = pm;    \
        }                                                                     \
    __syncthreads();                                                          \
    {                                                                         \
        char* qb = tbuf;                                                      \
        _Pragma("unroll")                                                     \
        for (int mr = 0; mr < 2; mr++)                                        \
            _Pragma("unroll")                                                 \
            for (int rg = 0; rg < 4; rg++) {                                  \
                int lrow = wm * 32 + mr * 16 + lhi * 4 + rg;                  \
                float m4 = fmaxf(fmaxf(rmax[lrow][0], rmax[lrow][1]),         \
                                 fmaxf(rmax[lrow][2], rmax[lrow][3]));        \
                float inv = (m4 > 0.f) ? 127.f / m4 : 0.f;                    \
                _Pragma("unroll")                                             \
                for (int nr = 0; nr < 8; nr++) {                              \
                    int col = wn * 128 + nr * 16 + l15;                       \
                    float v = (SIGNED) ? acc[mr][nr][rg]                      \
                                       : fmaxf(acc[mr][nr][rg], 0.f);         \
                    int q = (int)rintf(v * inv);                              \
                    q = (q > 127) ? 127 : ((q < -127) ? -127 : q);            \
                    qb[lrow * HIDDEN + col] = (char)q;                        \
                }                                                             \
            }                                                                 \
        __syncthreads();                                                      \
        int grow = m0 + rs;                                                   \
        if (grow < M) {                                                       \
            _Pragma("unroll")                                                 \
            for (int i = 0; i < 4; i++) {                                     \
                c8x16 vq = *reinterpret_cast<const c8x16*>(                   \
                    &qb[rs * HIDDEN + oc * 64 + i * 16]);                     \
                *reinterpret_cast<c8x16*>(                                    \
                    &(QOUT)[(size_t)grow * HIDDEN + oc * 64 + i * 16]) = vq;  \
            }                                                                 \
            if (oc == 0) {                                                    \
                float m4 = fmaxf(fmaxf(rmax[rs][0], rmax[rs][1]),             \
                                 fmaxf(rmax[rs][2], rmax[rs][3]));            \
                (QSC)[grow] = (m4 > 0.f) ? m4 / 127.f : 0.f;                  \
            }                                                                 \
        }                                                                     \
        __syncthreads();                                                      \
    }                                                                         \
} while (0)

    // ---- stage A: atomf (k<133) + fused bond gather (k 160..173) + flags ----
    {
        int grow = m0 + rs;
        bool ok = grow < M;
        float rsum = 0.f;
        int nb[MAX_NB];
        bool needB = ok && (oc == 4 || oc == 5);   // chunks 20,21 hold bond sums
        if (needB) {
            #pragma unroll
            for (int j = 0; j < MAX_NB; j++)
                nb[j] = a2b[(size_t)grow * MAX_NB + j];
        }
        #pragma unroll
        for (int c8 = 0; c8 < 3; ++c8) {
            int ch = c8 * 8 + oc;                 // 0..23
            s16x8 o;
            #pragma unroll
            for (int e = 0; e < 8; e++) {
                int k = ch * 8 + e;
                float v = 0.f;
                if (ok) {
                    if (k < ATOM_FDIM) {
                        v = Af32[(size_t)grow * ATOM_FDIM + k];
                        rsum += v;
                    } else if (k >= 160 && k < 160 + BOND_FDIM) {
                        int kp = k - 160;
                        #pragma unroll
                        for (int j = 0; j < MAX_NB; j++)
                            v += fbonds[(size_t)nb[j] * FB_DIM + ATOM_FDIM + kp];
                    }
                }
                o[e] = (short)fb(v);
            }
            As[A_UNIT(ch, rs)] = o;
        }
        rsum += __shfl_xor(rsum, 1);
        rsum += __shfl_xor(rsum, 2);
        rsum += __shfl_xor(rsum, 4);
        if (oc == 0 && ok) flags[grow] = (rsum > 0.f) ? 1.f : 0.f;
    }
    __syncthreads();

    // ---- GEMM 1: acc = atomf @ Wi (tiles 0..4) ----
    #pragma unroll
    for (int tp = 0; tp < 5; ++tp) TMFMA(WiT, tp);

    // ---- msgQ = i8 quant(relu(acc)) (acc preserved) ----
    QUANT8(qout, qscale, false);

    // ---- bond tile: acc += bondsum @ Wh2 (WiT tile 5) -> acc = base ----
    TMFMA(WiT, 5);

    // ---- baseQ = i8 rowwise-absmax quant(acc) ----
    QUANT8(baseQ, bqscale, true);

    // ---- GEMM 2: acc = atomf @ Wo1 (tiles 0..4) ----
    #pragma unroll
    for (int mr = 0; mr < 2; mr++)
        #pragma unroll
        for (int nr = 0; nr < 8; nr++)
            acc[mr][nr] = (f32x4){0.f, 0.f, 0.f, 0.f};
    #pragma unroll
    for (int tp = 0; tp < 5; ++tp) TMFMA(Wo1T, tp);

    // ---- foB = bf16(acc + b_o) via LDS transpose (nontemporal) ----
    unsigned short* tb = reinterpret_cast<unsigned short*>(tbuf); // [32][TROW]
    #pragma unroll
    for (int mr = 0; mr < 2; ++mr) {
        __syncthreads();
        #pragma unroll
        for (int nr = 0; nr < 8; nr++) {
            int col = wn * 128 + nr * 16 + l15;
            float bv = bias[col];
            #pragma unroll
            for (int rg = 0; rg < 4; rg++) {
                int lr = wm * 16 + lhi * 4 + rg;
                tb[lr * TROW + col] = fb(acc[mr][nr][rg] + bv);
            }
        }
        __syncthreads();
        #pragma unroll
        for (int i = 0; i < 4; i++) {
            int c  = i * 512 + t;
            int lr = c >> 6, ck = c & 63;
            int grow = m0 + ((lr >> 4) * 32) + mr * 16 + (lr & 15);
            if (grow < M) {
                s16x8 v = *reinterpret_cast<const s16x8*>(&tb[lr * TROW + ck * 8]);
                __builtin_nontemporal_store(v,
                    reinterpret_cast<s16x8*>(&foB[(size_t)grow * HIDDEN + ck * 8]));
            }
        }
    }
#undef QUANT8
#undef TMFMA
}

// ---------------------------------------------------------------------------
// i8 dense GEMM, BMI=128 x 512: Y = (scA.Aq) @ (wsc.Wq), 8 K=64 tiles.
// ---------------------------------------------------------------------------
__global__ __launch_bounds__(512, 2) void igemm(
    const signed char* __restrict__ Aq, const float* __restrict__ Ascale,
    const int* __restrict__ Wq, const float* __restrict__ wsc,
    signed char* __restrict__ qout, float* __restrict__ qscale,
    int M)
{
    __shared__ char qb[BMI * HIDDEN];       // 64 KB
    __shared__ float rmax[BMI][4];

    const int t    = threadIdx.x;
    const int m0   = blockIdx.x * BMI;
    const int lane = t & 63;
    const int l15  = lane & 15, lhi = lane >> 4;
    const int w    = t >> 6, wm = w >> 2, wn = w & 3;

    int r[4];
    #pragma unroll
    for (int i = 0; i < 4; i++) {
        int rr = m0 + wm * 64 + i * 16 + l15;
        r[i] = (rr < M) ? rr : (M - 1);
    }

    i32x4 acc[4][8];
    #pragma unroll
    for (int mr = 0; mr < 4; mr++)
        #pragma unroll
        for (int nr = 0; nr < 8; nr++)
            acc[mr][nr] = (i32x4){0, 0, 0, 0};

#define LOADA_I(A_, TILE) do {                                                \
    _Pragma("unroll")                                                         \
    for (int mr_ = 0; mr_ < 4; mr_++)                                         \
        A_[mr_] = *reinterpret_cast<const i32x4*>(                            \
            Aq + (size_t)r[mr_] * HIDDEN + (TILE) * 64 + lhi * 16);           \
} while (0)

#define LOADB_I(B_, TILE) do {                                                \
    const i32x4* bb_ = reinterpret_cast<const i32x4*>(Wq)                     \
        + (size_t)(TILE) * 2048 + ((wn * 128 + l15) * 4 + lhi);               \
    _Pragma("unroll")                                                         \
    for (int nr_ = 0; nr_ < 8; nr_++) B_[nr_] = bb_[nr_ * 64];                \
} while (0)

#define MFMA_I(A_, B_) do {                                                   \
    _Pragma("unroll")                                                         \
    for (int nr_ = 0; nr_ < 8; nr_++)                                         \
        _Pragma("unroll")                                                     \
        for (int mr_ = 0; mr_ < 4; mr_++)                                     \
            acc[mr_][nr_] = __builtin_amdgcn_mfma_i32_16x16x64_i8(A_[mr_], B_[nr_], acc[mr_][nr_], 0, 0, 0); \
} while (0)

    {
        i32x4 aA[4], aB[4], bA[8], bB[8];
        LOADA_I(aA, 0); LOADB_I(bA, 0);
        LOADA_I(aB, 1); LOADB_I(bB, 1);
        MFMA_I(aA, bA);
        LOADA_I(aA, 2); LOADB_I(bA, 2);
        MFMA_I(aB, bB);
        LOADA_I(aB, 3); LOADB_I(bB, 3);
        MFMA_I(aA, bA);
        LOADA_I(aA, 4); LOADB_I(bA, 4);
        MFMA_I(aB, bB);
        LOADA_I(aB, 5); LOADB_I(bB, 5);
        MFMA_I(aA, bA);
        LOADA_I(aA, 6); LOADB_I(bA, 6);
        MFMA_I(aB, bB);
        LOADA_I(aB, 7); LOADB_I(bB, 7);
        MFMA_I(aA, bA);
        MFMA_I(aB, bB);
    }

    float wscL[8];
    #pragma unroll
    for (int nr = 0; nr < 8; nr++) wscL[nr] = wsc[wn * 128 + nr * 16 + l15];

    #pragma unroll
    for (int mr = 0; mr < 4; mr++)
        #pragma unroll
        for (int rg = 0; rg < 4; rg++) {
            float pm = 0.f;
            #pragma unroll
            for (int nr = 0; nr < 8; nr++)
                pm = fmaxf(pm, fabsf((float)acc[mr][nr][rg]) * wscL[nr]);
            pm = fmaxf(pm, __shfl_xor(pm, 1));
            pm = fmaxf(pm, __shfl_xor(pm, 2));
            pm = fmaxf(pm, __shfl_xor(pm, 4));
            pm = fmaxf(pm, __shfl_xor(pm, 8));
            if (l15 == 0) rmax[wm * 64 + mr * 16 + lhi * 4 + rg][wn] = pm;
        }
    __syncthreads();

    #pragma unroll
    for (int mr = 0; mr < 4; mr++)
        #pragma unroll
        for (int rg = 0; rg < 4; rg++) {
            int lrow = wm * 64 + mr * 16 + lhi * 4 + rg;
            float m4 = fmaxf(fmaxf(rmax[lrow][0], rmax[lrow][1]),
                             fmaxf(rmax[lrow][2], rmax[lrow][3]));
            float inv = (m4 > 0.f) ? 127.f / m4 : 0.f;
            #pragma unroll
            for (int nr = 0; nr < 8; nr++) {
                int col = wn * 128 + nr * 16 + l15;
                int q = (int)rintf((float)acc[mr][nr][rg] * wscL[nr] * inv);
                q = (q > 127) ? 127 : ((q < -127) ? -127 : q);
                qb[lrow * HIDDEN + col] = (char)q;
            }
        }
    __syncthreads();

    {
        int rs2 = t >> 2, oc4 = t & 3;
        int grow = m0 + rs2;
        if (grow < M) {
            #pragma unroll
            for (int i = 0; i < 8; i++) {
                c8x16 vq = *reinterpret_cast<const c8x16*>(
                    &qb[rs2 * HIDDEN + oc4 * 128 + i * 16]);
                *reinterpret_cast<c8x16*>(
                    &qout[(size_t)grow * HIDDEN + oc4 * 128 + i * 16]) = vq;
            }
            if (oc4 == 0) {
                float m4 = fmaxf(fmaxf(rmax[rs2][0], rmax[rs2][1]),
                                 fmaxf(rmax[rs2][2], rmax[rs2][3]));
                qscale[grow] = Ascale[grow] * ((m4 > 0.f) ? m4 / 127.f : 0.f);
            }
        }
    }
#undef MFMA_I
#undef LOADB_I
#undef LOADA_I
}

// ---------------------------------------------------------------------------
// Iteration gather: s = gather6(Y) + bsc[a]*baseQ[a]; msg' = i8quant(relu(s)).
// ---------------------------------------------------------------------------
__global__ __launch_bounds__(256) void gath_k(
    const signed char* __restrict__ Yq, const float* __restrict__ ysc,
    const int* __restrict__ a2a,
    const signed char* __restrict__ baseQ, const float* __restrict__ bsc,
    signed char* __restrict__ qout, float* __restrict__ qscale,
    int M)
{
    int a    = (blockIdx.x * 256 + threadIdx.x) >> 6;
    int lane = threadIdx.x & 63;
    if (a >= M) return;

    float s[8] = {0.f, 0.f, 0.f, 0.f, 0.f, 0.f, 0.f, 0.f};
    #pragma unroll
    for (int j = 0; j < MAX_NB; j++) {
        int n    = a2a[(size_t)a * MAX_NB + j];
        float sc = ysc[n];
        s8x8 v = *reinterpret_cast<const s8x8*>(Yq + (size_t)n * HIDDEN + lane * 8);
        #pragma unroll
        for (int e = 0; e < 8; e++) s[e] += sc * (float)v[e];
    }
    {
        float sb = bsc[a];
        s8x8 b = *reinterpret_cast<const s8x8*>(baseQ + (size_t)a * HIDDEN + lane * 8);
        #pragma unroll
        for (int e = 0; e < 8; e++)
            s[e] = fmaxf(s[e] + sb * (float)b[e], 0.f);
    }

    float mx = s[0];
    #pragma unroll
    for (int e = 1; e < 8; e++) mx = fmaxf(mx, s[e]);
    #pragma unroll
    for (int off = 1; off < 64; off <<= 1)
        mx = fmaxf(mx, __shfl_xor(mx, off));
    float inv = (mx > 0.f) ? 127.f / mx : 0.f;
    s8x8 q;
    #pragma unroll
    for (int e = 0; e < 8; e++) {
        int qi = (int)(s[e] * inv + 0.5f);
        q[e] = (char)((qi > 127) ? 127 : qi);
    }
    *reinterpret_cast<s8x8*>(qout + (size_t)a * HIDDEN + lane * 8) = q;
    if (lane == 0) qscale[a] = (mx > 0.f) ? mx / 127.f : 0.f;
}

// ---------------------------------------------------------------------------
// Fused final gather + segment mean: block per molecule, thread = column.
// ---------------------------------------------------------------------------
__global__ __launch_bounds__(512) void gseg_k(
    const signed char* __restrict__ Yq, const float* __restrict__ ysc,
    const int* __restrict__ a2a,
    const unsigned short* __restrict__ fo,
    const float* __restrict__ flags,
    const int* __restrict__ mol_ids,
    float* __restrict__ out, int M, int NM)
{
    int m = blockIdx.x;
    int t = threadIdx.x;
    int lo = 0, hi = M;
    while (lo < hi) { int mid = (lo + hi) >> 1; if (mol_ids[mid] < m) lo = mid + 1; else hi = mid; }
    int s = lo;
    lo = 0; hi = M;
    while (lo < hi) { int mid = (lo + hi) >> 1; if (mol_ids[mid] < m + 1) lo = mid + 1; else hi = mid; }
    int e = lo;

    float acc = 0.f;
    #pragma unroll 4
    for (int a = s; a < e; a++) {
        const int* nb = a2a + (size_t)a * MAX_NB;
        float v = uf(__builtin_nontemporal_load(&fo[(size_t)a * HIDDEN + t]));
        #pragma unroll
        for (int j = 0; j < MAX_NB; j++) {
            int n = nb[j];
            v += ysc[n] * (float)Yq[(size_t)n * HIDDEN + t];
        }
        acc += fmaxf(v, 0.f);
    }

    float nzp = 0.f;
    for (int a = s + t; a < e; a += 512)
        nzp += __builtin_nontemporal_load(&flags[a]);
    __shared__ float red[512];
    red[t] = nzp; __syncthreads();
    for (int off = 256; off; off >>= 1) { if (t < off) red[t] += red[t + off]; __syncthreads(); }

    int cnt = e - s;
    float inv = 1.f / fmaxf((float)cnt, 1.f);
    out[(size_t)m * HIDDEN + t] = acc * inv;
    if (t == 0) {
        out[(size_t)NM * HIDDEN + 2 * m]     = red[0];
        out[(size_t)NM * HIDDEN + 2 * m + 1] = (float)cnt;
    }
}

// ---------------------------------------------------------------------------
extern "C" void kernel_launch(void* const* d_in, const int* in_sizes, int n_in,
                              void* d_out, int out_size, void* d_ws, size_t ws_size,
                              hipStream_t stream)
{
    const float* atomf   = (const float*)d_in[0];
    const float* f_bonds = (const float*)d_in[1];
    const int*   a2a     = (const int*)d_in[2];
    const int*   a2b     = (const int*)d_in[3];
    const int*   mol_ids = (const int*)d_in[4];
    const float* W_i     = (const float*)d_in[5];
    const float* W_h     = (const float*)d_in[6];
    const float* W_o     = (const float*)d_in[7];
    const float* b_o     = (const float*)d_in[8];
    float* out = (float*)d_out;

    const int M  = in_sizes[2] / MAX_NB;   // 100000
    const int NM = 1000;
    const size_t SZ = (size_t)M * HIDDEN;

    const float* Wh2f  = W_h + (size_t)HIDDEN * HIDDEN;    // [14][512] f32
    const float* Wo2f  = W_o + (size_t)ATOM_FDIM * HIDDEN;

    // ---- workspace layout ----
    const size_t TCH = HIDDEN * 32;                 // ushorts per bf16 tile
    unsigned short* WiT  = (unsigned short*)d_ws;   // 6 tiles (Wi + Wh2)
    unsigned short* Wo1T = WiT + 6 * TCH;           // 5 tiles
    signed char*    Wh1Q = (signed char*)(Wo1T + 5 * TCH);   // 256 KB
    signed char*    Wo2Q = Wh1Q + HIDDEN * HIDDEN;           // 256 KB
    float* wscH = (float*)(Wo2Q + HIDDEN * HIDDEN);
    float* wscO = wscH + HIDDEN;
    char* p = (char*)(wscO + HIDDEN);
    signed char*    baseQ = (signed char*)p;    p += SZ;      // i8 base
    unsigned short* foB   = (unsigned short*)p; p += SZ * 2;  // bf16 fo
    signed char*    msgQ  = (signed char*)p;    p += SZ;      // i8 messages
    signed char*    Yq    = (signed char*)p;    p += SZ;      // i8 Y
    float* scaleM = (float*)p; p += (size_t)M * 4;
    float* scaleY = (float*)p; p += (size_t)M * 4;
    float* bqsc   = (float*)p; p += (size_t)M * 4;
    float* flags  = (float*)p;

    const int gA  = (M + 3) / 4;
    const int gG  = (M + BM - 1) / BM;              // 1563
    const int gGI = (M + BMI - 1) / BMI;            // 782

    // ---- weight conversion ----
    cvt_w<<<(5 * 2048 + 255) / 256, 256, 0, stream>>>(W_i, WiT, ATOM_FDIM, 5 * 2048);
    cvt_w<<<(1 * 2048 + 255) / 256, 256, 0, stream>>>(Wh2f, WiT + 5 * TCH, BOND_FDIM, 2048);
    cvt_w<<<(5 * 2048 + 255) / 256, 256, 0, stream>>>(W_o, Wo1T, ATOM_FDIM, 5 * 2048);
    cvt8_k<<<HIDDEN, 256, 0, stream>>>(W_h,  Wh1Q, wscH);
    cvt8_k<<<HIDDEN, 256, 0, stream>>>(Wo2f, Wo2Q, wscO);

    // prologue: baseQ (= i8(inp + bond)), foB, msgQ, flags (bond gather fused)
    pro_k<<<gG, 512, 0, stream>>>(atomf, f_bonds, a2b, WiT, Wo1T, b_o,
                                  baseQ, bqsc, foB, msgQ, scaleM, flags, M);
    // 3 iters: Y = msg@Wh1 (i8 dense) ; msg' = i8quant(relu(base + gather6(Y)))
    for (int it = 0; it < 3; ++it) {
        igemm<<<gGI, 512, 0, stream>>>(msgQ, scaleM, (const int*)Wh1Q, wscH,
                                       Yq, scaleY, M);
        gath_k<<<gA, 256, 0, stream>>>(Yq, scaleY, a2a, baseQ, bqsc,
                                       msgQ, scaleM, M);
    }
    // Yo = msg3@Wo2 ; fused final gather + segment mean (+ nz from flags)
    igemm<<<gGI, 512, 0, stream>>>(msgQ, scaleM, (const int*)Wo2Q, wscO,
                                   Yq, scaleY, M);
    gseg_k<<<NM, 512, 0, stream>>>(Yq, scaleY, a2a, foB, flags,
                                   mol_ids, out, M, NM);
}

// Round 21
// 897.337 us; speedup vs baseline: 1.0224x; 1.0224x over previous
//
#include <hip/hip_runtime.h>
#include <hip/hip_bf16.h>
#include <cstddef>

#define HIDDEN 512
#define ATOM_FDIM 133
#define BOND_FDIM 14
#define FB_DIM 147
#define MAX_NB 6
#define BM 64
#define BMI 128     // igemm row tile
#define TROW 520    // padded bf16 row pitch for transpose buffer
#define NCH 24      // A chunks: K=192 pad (tiles 0..5; tile5 = bsum x Wh2)

typedef __attribute__((ext_vector_type(8)))  short         s16x8;
typedef __attribute__((ext_vector_type(16))) char          c8x16;
typedef __attribute__((ext_vector_type(8)))  signed char   s8x8;
typedef __attribute__((ext_vector_type(4)))  float         f32x4;
typedef __attribute__((ext_vector_type(4)))  int           i32x4;

__device__ __forceinline__ float uf(unsigned short u) {
    return __uint_as_float(((unsigned)u) << 16);
}
__device__ __forceinline__ unsigned short fb(float f) {
    __hip_bfloat16 h = __float2bfloat16(f);
    return *reinterpret_cast<unsigned short*>(&h);
}

// LDS A tile: chunks(16B) x 64 rows, XOR-swizzled.
#define A_UNIT(ch, row) (((ch) << 6) + ((row) ^ ((ch) & 7)))

// ---------------------------------------------------------------------------
// bf16 weight convert: f32 [Ksrc][512] -> bf16 MFMA-fragment order (K=32 tiles)
// ---------------------------------------------------------------------------
__global__ __launch_bounds__(256) void cvt_w(const float* __restrict__ src,
                                             unsigned short* __restrict__ dst,
                                             int Ksrc, int nchunks)
{
    int c = blockIdx.x * 256 + threadIdx.x;
    if (c >= nchunks) return;
    int tile = c >> 11, pc = c & 2047, n = pc >> 2, s = pc & 3;
    s16x8 o;
    #pragma unroll
    for (int e = 0; e < 8; e++) {
        int k = tile * 32 + s * 8 + e;
        float v = (k < Ksrc) ? src[(size_t)k * HIDDEN + n] : 0.f;
        o[e] = (short)fb(v);
    }
    reinterpret_cast<s16x8*>(dst)[c] = o;
}

// ---------------------------------------------------------------------------
// Fused per-column scale + i8 convert: one block per column n.
// ---------------------------------------------------------------------------
__global__ __launch_bounds__(256) void cvt8_k(const float* __restrict__ src,
                                              signed char* __restrict__ dst,
                                              float* __restrict__ wsc)
{
    int n = blockIdx.x;
    float v0 = src[(size_t)threadIdx.x * HIDDEN + n];
    float v1 = src[(size_t)(threadIdx.x + 256) * HIDDEN + n];
    float m = fmaxf(fabsf(v0), fabsf(v1));
    #pragma unroll
    for (int off = 32; off; off >>= 1) m = fmaxf(m, __shfl_down(m, off));
    __shared__ float red[4];
    __shared__ float bcast;
    if ((threadIdx.x & 63) == 0) red[threadIdx.x >> 6] = m;
    __syncthreads();
    if (threadIdx.x == 0) {
        m = fmaxf(fmaxf(red[0], red[1]), fmaxf(red[2], red[3]));
        bcast = m;
        wsc[n] = m / 127.f;
    }
    __syncthreads();
    float mx = bcast;
    float inv = (mx > 0.f) ? 127.f / mx : 0.f;
    #pragma unroll
    for (int h = 0; h < 2; h++) {
        int k = threadIdx.x + h * 256;
        float v = (h == 0) ? v0 : v1;
        int q = (int)rintf(v * inv);
        q = (q > 127) ? 127 : ((q < -127) ? -127 : q);
        int tile = k >> 6, g = (k & 63) >> 4, e = k & 15;
        dst[((size_t)tile * 2048 + n * 4 + g) * 16 + e] = (char)q;
    }
}

// ---------------------------------------------------------------------------
// bsum[a][k<16] = sum_j f_bonds[a2b[a][j]][133+k]  (k<14; 14,15 = 0)
// ---------------------------------------------------------------------------
__global__ __launch_bounds__(256) void bsum_k(const float* __restrict__ f_bonds,
                                              const int* __restrict__ a2b,
                                              float* __restrict__ bsum, int M)
{
    int tid = blockIdx.x * 256 + threadIdx.x;
    int a = tid >> 4, k = tid & 15;
    if (a >= M) return;
    float s = 0.f;
    if (k < BOND_FDIM) {
        #pragma unroll
        for (int j = 0; j < MAX_NB; j++) {
            int b = a2b[(size_t)a * MAX_NB + j];
            s += f_bonds[(size_t)b * FB_DIM + ATOM_FDIM + k];
        }
    }
    bsum[(size_t)a * 16 + k] = s;
}

// ---------------------------------------------------------------------------
// Prologue GEMM, sequential accumulator, half-width B buffering:
//   stage A once: atomf (k<133) + bsum (k in [160,174))
//   acc = A@WiT[0..4]        -> msgQ = i8 quant(relu(acc)), flags
//   acc += A@WiT[5] (=Wh2)   -> baseQ = i8 rowwise-absmax quant(acc)
//   acc  = A@Wo1T[0..4]      -> foB  = bf16(acc + b_o)  [nontemporal]
// ---------------------------------------------------------------------------
__global__ __launch_bounds__(512, 4) void pro_k(
    const float* __restrict__ Af32,
    const float* __restrict__ bsum,
    const unsigned short* __restrict__ WiT,    // 6 tiles
    const unsigned short* __restrict__ Wo1T,   // 5 tiles
    const float* __restrict__ bias,
    signed char* __restrict__ baseQ, float* __restrict__ bqscale,
    unsigned short* __restrict__ foB,
    signed char* __restrict__ qout, float* __restrict__ qscale,
    float* __restrict__ flags,
    int M)
{
    __shared__ s16x8 As[NCH * 64];               // 24 KB, lives whole kernel
    __shared__ char  tbuf[TROW * 32 * 2];        // 33.3 KB: transpose / quant
    __shared__ float rmax[BM][4];

    const int t    = threadIdx.x;
    const int m0   = blockIdx.x * BM;
    const int lane = t & 63;
    const int l15  = lane & 15, lhi = lane >> 4;
    const int w    = t >> 6, wm = w >> 2, wn = w & 3;
    const int rs   = t >> 3, oc = t & 7;

    f32x4 acc[2][8];
    #pragma unroll
    for (int mr = 0; mr < 2; mr++)
        #pragma unroll
        for (int nr = 0; nr < 8; nr++)
            acc[mr][nr] = (f32x4){0.f, 0.f, 0.f, 0.f};

    // one MFMA K-tile with HALF-width (4-fragment) B buffering
#define TMFMA(WTP, TILE) do {                                                 \
    s16x8 a0_ = As[A_UNIT((TILE) * 4 + lhi, wm * 32 + l15)];                  \
    s16x8 a1_ = As[A_UNIT((TILE) * 4 + lhi, wm * 32 + 16 + l15)];             \
    _Pragma("unroll")                                                         \
    for (int h_ = 0; h_ < 2; ++h_) {                                          \
        s16x8 b_[4];                                                          \
        const s16x8* bb_ = reinterpret_cast<const s16x8*>(                    \
            (WTP) + (size_t)(TILE) * (HIDDEN * 32))                           \
            + ((wn * 128 + h_ * 64 + l15) * 4 + lhi);                         \
        _Pragma("unroll")                                                     \
        for (int nr_ = 0; nr_ < 4; nr_++) b_[nr_] = bb_[nr_ * 64];            \
        _Pragma("unroll")                                                     \
        for (int nr_ = 0; nr_ < 4; nr_++) {                                   \
            acc[0][h_ * 4 + nr_] = __builtin_amdgcn_mfma_f32_16x16x32_bf16(   \
                a0_, b_[nr_], acc[0][h_ * 4 + nr_], 0, 0, 0);                 \
            acc[1][h_ * 4 + nr_] = __builtin_amdgcn_mfma_f32_16x16x32_bf16(   \
                a1_, b_[nr_], acc[1][h_ * 4 + nr_], 0, 0, 0);                 \
        }                                                                     \
    }                                                                         \
} while (0)

    // i8 row-quant of acc into QOUT/QSC.  SIGNED: use |.|; UNSIGNED: relu.
#define QUANT8(QOUT, QSC, SIGNED) do {                                        \
    _Pragma("unroll")                                                         \
    for (int mr = 0; mr < 2; mr++)                                            \
        _Pragma("unroll")                                                     \
        for (int rg = 0; rg < 4; rg++) {                                      \
            float pm = 0.f;                                                   \
            _Pragma("unroll")                                                 \
            for (int nr = 0; nr < 8; nr++)                                    \
                pm = fmaxf(pm, (SIGNED) ? fabsf(acc[mr][nr][rg])              \
                                        : acc[mr][nr][rg]);                   \
            pm = fmaxf(pm, __shfl_xor(pm, 1));                                \
            pm = fmaxf(pm, __shfl_xor(pm, 2));                                \
            pm = fmaxf(pm, __shfl_xor(pm, 4));                                \
            pm = fmaxf(pm, __shfl_xor(pm, 8));                                \
            if (l15 == 0) rmax[wm * 32 + mr * 16 + lhi * 4 + rg][wn] = pm;    \
        }                                                                     \
    __syncthreads();                                                          \
    {                                                                         \
        char* qb = tbuf;                                                      \
        _Pragma("unroll")                                                     \
        for (int mr = 0; mr < 2; mr++)                                        \
            _Pragma("unroll")                                                 \
            for (int rg = 0; rg < 4; rg++) {                                  \
                int lrow = wm * 32 + mr * 16 + lhi * 4 + rg;                  \
                float m4 = fmaxf(fmaxf(rmax[lrow][0], rmax[lrow][1]),         \
                                 fmaxf(rmax[lrow][2], rmax[lrow][3]));        \
                float inv = (m4 > 0.f) ? 127.f / m4 : 0.f;                    \
                _Pragma("unroll")                                             \
                for (int nr = 0; nr < 8; nr++) {                              \
                    int col = wn * 128 + nr * 16 + l15;                       \
                    float v = (SIGNED) ? acc[mr][nr][rg]                      \
                                       : fmaxf(acc[mr][nr][rg], 0.f);         \
                    int q = (int)rintf(v * inv);                              \
                    q = (q > 127) ? 127 : ((q < -127) ? -127 : q);            \
                    qb[lrow * HIDDEN + col] = (char)q;                        \
                }                                                             \
            }                                                                 \
        __syncthreads();                                                      \
        int grow = m0 + rs;                                                   \
        if (grow < M) {                                                       \
            _Pragma("unroll")                                                 \
            for (int i = 0; i < 4; i++) {                                     \
                c8x16 vq = *reinterpret_cast<const c8x16*>(                   \
                    &qb[rs * HIDDEN + oc * 64 + i * 16]);                     \
                *reinterpret_cast<c8x16*>(                                    \
                    &(QOUT)[(size_t)grow * HIDDEN + oc * 64 + i * 16]) = vq;  \
            }                                                                 \
            if (oc == 0) {                                                    \
                float m4 = fmaxf(fmaxf(rmax[rs][0], rmax[rs][1]),             \
                                 fmaxf(rmax[rs][2], rmax[rs][3]));            \
                (QSC)[grow] = (m4 > 0.f) ? m4 / 127.f : 0.f;                  \
            }                                                                 \
        }                                                                     \
        __syncthreads();                                                      \
    }                                                                         \
} while (0)

    // ---- stage A: atomf (k<133) + bsum (k 160..173) + row-sum flags ----
    {
        int grow = m0 + rs;
        bool ok = grow < M;
        float rsum = 0.f;
        #pragma unroll
        for (int c8 = 0; c8 < 3; ++c8) {
            int ch = c8 * 8 + oc;                 // 0..23
            s16x8 o;
            #pragma unroll
            for (int e = 0; e < 8; e++) {
                int k = ch * 8 + e;
                float v = 0.f;
                if (ok) {
                    if (k < ATOM_FDIM) { v = Af32[(size_t)grow * ATOM_FDIM + k]; rsum += v; }
                    else if (k >= 160 && k < 160 + BOND_FDIM)
                        v = bsum[(size_t)grow * 16 + (k - 160)];
                }
                o[e] = (short)fb(v);
            }
            As[A_UNIT(ch, rs)] = o;
        }
        rsum += __shfl_xor(rsum, 1);
        rsum += __shfl_xor(rsum, 2);
        rsum += __shfl_xor(rsum, 4);
        if (oc == 0 && ok) flags[grow] = (rsum > 0.f) ? 1.f : 0.f;
    }
    __syncthreads();

    // ---- GEMM 1: acc = atomf @ Wi (tiles 0..4) ----
    #pragma unroll
    for (int tp = 0; tp < 5; ++tp) TMFMA(WiT, tp);

    // ---- msgQ = i8 quant(relu(acc)) (acc preserved) ----
    QUANT8(qout, qscale, false);

    // ---- bond tile: acc += bsum @ Wh2 (WiT tile 5) -> acc = base ----
    TMFMA(WiT, 5);

    // ---- baseQ = i8 rowwise-absmax quant(acc) ----
    QUANT8(baseQ, bqscale, true);

    // ---- GEMM 2: acc = atomf @ Wo1 (tiles 0..4) ----
    #pragma unroll
    for (int mr = 0; mr < 2; mr++)
        #pragma unroll
        for (int nr = 0; nr < 8; nr++)
            acc[mr][nr] = (f32x4){0.f, 0.f, 0.f, 0.f};
    #pragma unroll
    for (int tp = 0; tp < 5; ++tp) TMFMA(Wo1T, tp);

    // ---- foB = bf16(acc + b_o) via LDS transpose (nontemporal) ----
    unsigned short* tb = reinterpret_cast<unsigned short*>(tbuf); // [32][TROW]
    #pragma unroll
    for (int mr = 0; mr < 2; ++mr) {
        __syncthreads();
        #pragma unroll
        for (int nr = 0; nr < 8; nr++) {
            int col = wn * 128 + nr * 16 + l15;
            float bv = bias[col];
            #pragma unroll
            for (int rg = 0; rg < 4; rg++) {
                int lr = wm * 16 + lhi * 4 + rg;
                tb[lr * TROW + col] = fb(acc[mr][nr][rg] + bv);
            }
        }
        __syncthreads();
        #pragma unroll
        for (int i = 0; i < 4; i++) {
            int c  = i * 512 + t;
            int lr = c >> 6, ck = c & 63;
            int grow = m0 + ((lr >> 4) * 32) + mr * 16 + (lr & 15);
            if (grow < M) {
                s16x8 v = *reinterpret_cast<const s16x8*>(&tb[lr * TROW + ck * 8]);
                __builtin_nontemporal_store(v,
                    reinterpret_cast<s16x8*>(&foB[(size_t)grow * HIDDEN + ck * 8]));
            }
        }
    }
#undef QUANT8
#undef TMFMA
}

// ---------------------------------------------------------------------------
// i8 dense GEMM, BMI=128 x 512: Y = (scA.Aq) @ (wsc.Wq), 8 K=64 tiles.
// ---------------------------------------------------------------------------
__global__ __launch_bounds__(512, 2) void igemm(
    const signed char* __restrict__ Aq, const float* __restrict__ Ascale,
    const int* __restrict__ Wq, const float* __restrict__ wsc,
    signed char* __restrict__ qout, float* __restrict__ qscale,
    int M)
{
    __shared__ char qb[BMI * HIDDEN];       // 64 KB
    __shared__ float rmax[BMI][4];

    const int t    = threadIdx.x;
    const int m0   = blockIdx.x * BMI;
    const int lane = t & 63;
    const int l15  = lane & 15, lhi = lane >> 4;
    const int w    = t >> 6, wm = w >> 2, wn = w & 3;

    int r[4];
    #pragma unroll
    for (int i = 0; i < 4; i++) {
        int rr = m0 + wm * 64 + i * 16 + l15;
        r[i] = (rr < M) ? rr : (M - 1);
    }

    i32x4 acc[4][8];
    #pragma unroll
    for (int mr = 0; mr < 4; mr++)
        #pragma unroll
        for (int nr = 0; nr < 8; nr++)
            acc[mr][nr] = (i32x4){0, 0, 0, 0};

#define LOADA_I(A_, TILE) do {                                                \
    _Pragma("unroll")                                                         \
    for (int mr_ = 0; mr_ < 4; mr_++)                                         \
        A_[mr_] = *reinterpret_cast<const i32x4*>(                            \
            Aq + (size_t)r[mr_] * HIDDEN + (TILE) * 64 + lhi * 16);           \
} while (0)

#define LOADB_I(B_, TILE) do {                                                \
    const i32x4* bb_ = reinterpret_cast<const i32x4*>(Wq)                     \
        + (size_t)(TILE) * 2048 + ((wn * 128 + l15) * 4 + lhi);               \
    _Pragma("unroll")                                                         \
    for (int nr_ = 0; nr_ < 8; nr_++) B_[nr_] = bb_[nr_ * 64];                \
} while (0)

#define MFMA_I(A_, B_) do {                                                   \
    _Pragma("unroll")                                                         \
    for (int nr_ = 0; nr_ < 8; nr_++)                                         \
        _Pragma("unroll")                                                     \
        for (int mr_ = 0; mr_ < 4; mr_++)                                     \
            acc[mr_][nr_] = __builtin_amdgcn_mfma_i32_16x16x64_i8(A_[mr_], B_[nr_], acc[mr_][nr_], 0, 0, 0); \
} while (0)

    {
        i32x4 aA[4], aB[4], bA[8], bB[8];
        LOADA_I(aA, 0); LOADB_I(bA, 0);
        LOADA_I(aB, 1); LOADB_I(bB, 1);
        MFMA_I(aA, bA);
        LOADA_I(aA, 2); LOADB_I(bA, 2);
        MFMA_I(aB, bB);
        LOADA_I(aB, 3); LOADB_I(bB, 3);
        MFMA_I(aA, bA);
        LOADA_I(aA, 4); LOADB_I(bA, 4);
        MFMA_I(aB, bB);
        LOADA_I(aB, 5); LOADB_I(bB, 5);
        MFMA_I(aA, bA);
        LOADA_I(aA, 6); LOADB_I(bA, 6);
        MFMA_I(aB, bB);
        LOADA_I(aB, 7); LOADB_I(bB, 7);
        MFMA_I(aA, bA);
        MFMA_I(aB, bB);
    }

    float wscL[8];
    #pragma unroll
    for (int nr = 0; nr < 8; nr++) wscL[nr] = wsc[wn * 128 + nr * 16 + l15];

    #pragma unroll
    for (int mr = 0; mr < 4; mr++)
        #pragma unroll
        for (int rg = 0; rg < 4; rg++) {
            float pm = 0.f;
            #pragma unroll
            for (int nr = 0; nr < 8; nr++)
                pm = fmaxf(pm, fabsf((float)acc[mr][nr][rg]) * wscL[nr]);
            pm = fmaxf(pm, __shfl_xor(pm, 1));
            pm = fmaxf(pm, __shfl_xor(pm, 2));
            pm = fmaxf(pm, __shfl_xor(pm, 4));
            pm = fmaxf(pm, __shfl_xor(pm, 8));
            if (l15 == 0) rmax[wm * 64 + mr * 16 + lhi * 4 + rg][wn] = pm;
        }
    __syncthreads();

    #pragma unroll
    for (int mr = 0; mr < 4; mr++)
        #pragma unroll
        for (int rg = 0; rg < 4; rg++) {
            int lrow = wm * 64 + mr * 16 + lhi * 4 + rg;
            float m4 = fmaxf(fmaxf(rmax[lrow][0], rmax[lrow][1]),
                             fmaxf(rmax[lrow][2], rmax[lrow][3]));
            float inv = (m4 > 0.f) ? 127.f / m4 : 0.f;
            #pragma unroll
            for (int nr = 0; nr < 8; nr++) {
                int col = wn * 128 + nr * 16 + l15;
                int q = (int)rintf((float)acc[mr][nr][rg] * wscL[nr] * inv);
                q = (q > 127) ? 127 : ((q < -127) ? -127 : q);
                qb[lrow * HIDDEN + col] = (char)q;
            }
        }
    __syncthreads();

    {
        int rs2 = t >> 2, oc4 = t & 3;
        int grow = m0 + rs2;
        if (grow < M) {
            #pragma unroll
            for (int i = 0; i < 8; i++) {
                c8x16 vq = *reinterpret_cast<const c8x16*>(
                    &qb[rs2 * HIDDEN + oc4 * 128 + i * 16]);
                *reinterpret_cast<c8x16*>(
                    &qout[(size_t)grow * HIDDEN + oc4 * 128 + i * 16]) = vq;
            }
            if (oc4 == 0) {
                float m4 = fmaxf(fmaxf(rmax[rs2][0], rmax[rs2][1]),
                                 fmaxf(rmax[rs2][2], rmax[rs2][3]));
                qscale[grow] = Ascale[grow] * ((m4 > 0.f) ? m4 / 127.f : 0.f);
            }
        }
    }
#undef MFMA_I
#undef LOADB_I
#undef LOADA_I
}

// ---------------------------------------------------------------------------
// Iteration gather: s = gather6(Y) + bsc[a]*baseQ[a]; msg' = i8quant(relu(s)).
// ---------------------------------------------------------------------------
__global__ __launch_bounds__(256) void gath_k(
    const signed char* __restrict__ Yq, const float* __restrict__ ysc,
    const int* __restrict__ a2a,
    const signed char* __restrict__ baseQ, const float* __restrict__ bsc,
    signed char* __restrict__ qout, float* __restrict__ qscale,
    int M)
{
    int a    = (blockIdx.x * 256 + threadIdx.x) >> 6;
    int lane = threadIdx.x & 63;
    if (a >= M) return;

    float s[8] = {0.f, 0.f, 0.f, 0.f, 0.f, 0.f, 0.f, 0.f};
    #pragma unroll
    for (int j = 0; j < MAX_NB; j++) {
        int n    = a2a[(size_t)a * MAX_NB + j];
        float sc = ysc[n];
        s8x8 v = *reinterpret_cast<const s8x8*>(Yq + (size_t)n * HIDDEN + lane * 8);
        #pragma unroll
        for (int e = 0; e < 8; e++) s[e] += sc * (float)v[e];
    }
    {
        float sb = bsc[a];
        s8x8 b = *reinterpret_cast<const s8x8*>(baseQ + (size_t)a * HIDDEN + lane * 8);
        #pragma unroll
        for (int e = 0; e < 8; e++)
            s[e] = fmaxf(s[e] + sb * (float)b[e], 0.f);
    }

    float mx = s[0];
    #pragma unroll
    for (int e = 1; e < 8; e++) mx = fmaxf(mx, s[e]);
    #pragma unroll
    for (int off = 1; off < 64; off <<= 1)
        mx = fmaxf(mx, __shfl_xor(mx, off));
    float inv = (mx > 0.f) ? 127.f / mx : 0.f;
    s8x8 q;
    #pragma unroll
    for (int e = 0; e < 8; e++) {
        int qi = (int)(s[e] * inv + 0.5f);
        q[e] = (char)((qi > 127) ? 127 : qi);
    }
    *reinterpret_cast<s8x8*>(qout + (size_t)a * HIDDEN + lane * 8) = q;
    if (lane == 0) qscale[a] = (mx > 0.f) ? mx / 127.f : 0.f;
}

// ---------------------------------------------------------------------------
// Fused final gather + segment mean: block per molecule, thread = column.
// ---------------------------------------------------------------------------
__global__ __launch_bounds__(512) void gseg_k(
    const signed char* __restrict__ Yq, const float* __restrict__ ysc,
    const int* __restrict__ a2a,
    const unsigned short* __restrict__ fo,
    const float* __restrict__ flags,
    const int* __restrict__ mol_ids,
    float* __restrict__ out, int M, int NM)
{
    int m = blockIdx.x;
    int t = threadIdx.x;
    int lo = 0, hi = M;
    while (lo < hi) { int mid = (lo + hi) >> 1; if (mol_ids[mid] < m) lo = mid + 1; else hi = mid; }
    int s = lo;
    lo = 0; hi = M;
    while (lo < hi) { int mid = (lo + hi) >> 1; if (mol_ids[mid] < m + 1) lo = mid + 1; else hi = mid; }
    int e = lo;

    float acc = 0.f;
    #pragma unroll 4
    for (int a = s; a < e; a++) {
        const int* nb = a2a + (size_t)a * MAX_NB;
        float v = uf(__builtin_nontemporal_load(&fo[(size_t)a * HIDDEN + t]));
        #pragma unroll
        for (int j = 0; j < MAX_NB; j++) {
            int n = nb[j];
            v += ysc[n] * (float)Yq[(size_t)n * HIDDEN + t];
        }
        acc += fmaxf(v, 0.f);
    }

    float nzp = 0.f;
    for (int a = s + t; a < e; a += 512)
        nzp += __builtin_nontemporal_load(&flags[a]);
    __shared__ float red[512];
    red[t] = nzp; __syncthreads();
    for (int off = 256; off; off >>= 1) { if (t < off) red[t] += red[t + off]; __syncthreads(); }

    int cnt = e - s;
    float inv = 1.f / fmaxf((float)cnt, 1.f);
    out[(size_t)m * HIDDEN + t] = acc * inv;
    if (t == 0) {
        out[(size_t)NM * HIDDEN + 2 * m]     = red[0];
        out[(size_t)NM * HIDDEN + 2 * m + 1] = (float)cnt;
    }
}

// ---------------------------------------------------------------------------
extern "C" void kernel_launch(void* const* d_in, const int* in_sizes, int n_in,
                              void* d_out, int out_size, void* d_ws, size_t ws_size,
                              hipStream_t stream)
{
    const float* atomf   = (const float*)d_in[0];
    const float* f_bonds = (const float*)d_in[1];
    const int*   a2a     = (const int*)d_in[2];
    const int*   a2b     = (const int*)d_in[3];
    const int*   mol_ids = (const int*)d_in[4];
    const float* W_i     = (const float*)d_in[5];
    const float* W_h     = (const float*)d_in[6];
    const float* W_o     = (const float*)d_in[7];
    const float* b_o     = (const float*)d_in[8];
    float* out = (float*)d_out;

    const int M  = in_sizes[2] / MAX_NB;   // 100000
    const int NM = 1000;
    const size_t SZ = (size_t)M * HIDDEN;

    const float* Wh2f  = W_h + (size_t)HIDDEN * HIDDEN;    // [14][512] f32
    const float* Wo2f  = W_o + (size_t)ATOM_FDIM * HIDDEN;

    // ---- workspace layout ----
    const size_t TCH = HIDDEN * 32;                 // ushorts per bf16 tile
    unsigned short* WiT  = (unsigned short*)d_ws;   // 6 tiles (Wi + Wh2)
    unsigned short* Wo1T = WiT + 6 * TCH;           // 5 tiles
    signed char*    Wh1Q = (signed char*)(Wo1T + 5 * TCH);   // 256 KB
    signed char*    Wo2Q = Wh1Q + HIDDEN * HIDDEN;           // 256 KB
    float* wscH = (float*)(Wo2Q + HIDDEN * HIDDEN);
    float* wscO = wscH + HIDDEN;
    char* p = (char*)(wscO + HIDDEN);
    signed char*    baseQ = (signed char*)p;    p += SZ;      // i8 base
    unsigned short* foB   = (unsigned short*)p; p += SZ * 2;  // bf16 fo
    signed char*    msgQ  = (signed char*)p;    p += SZ;      // i8 messages
    signed char*    Yq    = (signed char*)p;    p += SZ;      // i8 Y
    float* bsum   = (float*)p; p += (size_t)M * 16 * 4;       // 6.4 MB
    float* scaleM = (float*)p; p += (size_t)M * 4;
    float* scaleY = (float*)p; p += (size_t)M * 4;
    float* bqsc   = (float*)p; p += (size_t)M * 4;
    float* flags  = (float*)p;

    const int gA  = (M + 3) / 4;
    const int gG  = (M + BM - 1) / BM;              // 1563
    const int gGI = (M + BMI - 1) / BMI;            // 782

    // ---- weight conversion ----
    cvt_w<<<(5 * 2048 + 255) / 256, 256, 0, stream>>>(W_i, WiT, ATOM_FDIM, 5 * 2048);
    cvt_w<<<(1 * 2048 + 255) / 256, 256, 0, stream>>>(Wh2f, WiT + 5 * TCH, BOND_FDIM, 2048);
    cvt_w<<<(5 * 2048 + 255) / 256, 256, 0, stream>>>(W_o, Wo1T, ATOM_FDIM, 5 * 2048);
    cvt8_k<<<HIDDEN, 256, 0, stream>>>(W_h,  Wh1Q, wscH);
    cvt8_k<<<HIDDEN, 256, 0, stream>>>(Wo2f, Wo2Q, wscO);

    // bond sums -> staged into pro_k's A as K-tile 5
    bsum_k<<<(M * 16 + 255) / 256, 256, 0, stream>>>(f_bonds, a2b, bsum, M);
    // prologue: baseQ (= i8(inp + bond)), foB, msgQ, flags
    pro_k<<<gG, 512, 0, stream>>>(atomf, bsum, WiT, Wo1T, b_o,
                                  baseQ, bqsc, foB, msgQ, scaleM, flags, M);
    // 3 iters: Y = msg@Wh1 (i8 dense) ; msg' = i8quant(relu(base + gather6(Y)))
    for (int it = 0; it < 3; ++it) {
        igemm<<<gGI, 512, 0, stream>>>(msgQ, scaleM, (const int*)Wh1Q, wscH,
                                       Yq, scaleY, M);
        gath_k<<<gA, 256, 0, stream>>>(Yq, scaleY, a2a, baseQ, bqsc,
                                       msgQ, scaleM, M);
    }
    // Yo = msg3@Wo2 ; fused final gather + segment mean (+ nz from flags)
    igemm<<<gGI, 512, 0, stream>>>(msgQ, scaleM, (const int*)Wo2Q, wscO,
                                   Yq, scaleY, M);
    gseg_k<<<NM, 512, 0, stream>>>(Yq, scaleY, a2a, foB, flags,
                                   mol_ids, out, M, NM);
}